// Round 18
// baseline (2690.436 us; speedup 1.0000x reference)
//
#include <hip/hip_runtime.h>
#include <hip/hip_bf16.h>
#include <math.h>

#define N 8
#define Q 900
#define D 256
#define HB 200
#define WB 200
#define L 6
#define NH 8
#define P 4
#define HD 32
#define FF 512
#define NCLS 10
#define ODIM 18
#define HW (HB*WB)
#define NQ (N*Q)
#define NQD (NQ*D)
#define QD (Q*D)
#define SCALE 0.17677669529663687f

typedef __attribute__((ext_vector_type(4))) float f32x4;
typedef __attribute__((ext_vector_type(8))) short short8v;

__device__ __forceinline__ short bf16_of(float f) {
  __hip_bfloat16 h = __float2bfloat16(f);
  return __builtin_bit_cast(short, h);
}

// ---------------- slab f32 GEMM, 64x64 tile, 128 threads, 8x4 acc/thread, KC=64 ----------------
// ACT: 0 = none, 1 = relu
#define TM 64
#define TN 64
#define KCG 64

template <int ACT>
__global__ __launch_bounds__(128) void gemm_kernel(
    const float* __restrict__ A, const float* __restrict__ B,
    const float* __restrict__ bias, float* __restrict__ C,
    int M, int K, int Nc) {
  __shared__ float AsT[KCG][TM + 4];   // 17.4 KB
  __shared__ float Bs[KCG][TN + 4];    // 17.4 KB
  const int tid = threadIdx.x;         // 0..127
  const int tx = tid & 15;             // col group: cols tx*4..+3
  const int ty = tid >> 4;             // 0..7 row group: rows ty*8..+7
  const int m0 = blockIdx.x * TM, n0 = blockIdx.y * TN;

  float c[8][4] = {};

  for (int kc = 0; kc < K; kc += KCG) {
    // stage A: 64 rows x 64 k, transposed. thread: row tid>>1, k-base (tid&1)*32
    {
      int r = tid >> 1;
      int gr = m0 + r;
      int kb = (tid & 1) * 32;
#pragma unroll
      for (int q = 0; q < 8; ++q) {
        int k = kb + q * 4;
        float4 av = make_float4(0.f, 0.f, 0.f, 0.f);
        if (gr < M) av = *(const float4*)(A + (size_t)gr * K + kc + k);
        AsT[k + 0][r] = av.x; AsT[k + 1][r] = av.y;
        AsT[k + 2][r] = av.z; AsT[k + 3][r] = av.w;
      }
    }
    // stage B: 64 k x 64 cols; per instruction 16 lanes cover one row (coalesced)
    {
#pragma unroll
      for (int i = 0; i < 8; ++i) {
        int idx = i * 128 + tid;          // 0..1023
        int kr = idx >> 4;                // 0..63
        int c4 = (idx & 15) * 4;
        *(float4*)&Bs[kr][c4] = *(const float4*)(B + (size_t)(kc + kr) * Nc + n0 + c4);
      }
    }
    __syncthreads();
#pragma unroll 8
    for (int kk = 0; kk < KCG; ++kk) {
      float4 a0 = *(const float4*)&AsT[kk][ty * 8];
      float4 a1 = *(const float4*)&AsT[kk][ty * 8 + 4];
      float4 bv = *(const float4*)&Bs[kk][tx * 4];
      c[0][0] += a0.x * bv.x; c[0][1] += a0.x * bv.y; c[0][2] += a0.x * bv.z; c[0][3] += a0.x * bv.w;
      c[1][0] += a0.y * bv.x; c[1][1] += a0.y * bv.y; c[1][2] += a0.y * bv.z; c[1][3] += a0.y * bv.w;
      c[2][0] += a0.z * bv.x; c[2][1] += a0.z * bv.y; c[2][2] += a0.z * bv.z; c[2][3] += a0.z * bv.w;
      c[3][0] += a0.w * bv.x; c[3][1] += a0.w * bv.y; c[3][2] += a0.w * bv.z; c[3][3] += a0.w * bv.w;
      c[4][0] += a1.x * bv.x; c[4][1] += a1.x * bv.y; c[4][2] += a1.x * bv.z; c[4][3] += a1.x * bv.w;
      c[5][0] += a1.y * bv.x; c[5][1] += a1.y * bv.y; c[5][2] += a1.y * bv.z; c[5][3] += a1.y * bv.w;
      c[6][0] += a1.z * bv.x; c[6][1] += a1.z * bv.y; c[6][2] += a1.z * bv.z; c[6][3] += a1.z * bv.w;
      c[7][0] += a1.w * bv.x; c[7][1] += a1.w * bv.y; c[7][2] += a1.w * bv.z; c[7][3] += a1.w * bv.w;
    }
    __syncthreads();
  }

#pragma unroll
  for (int i = 0; i < 8; ++i) {
    int row = m0 + ty * 8 + i;
    if (row >= M) continue;
#pragma unroll
    for (int j = 0; j < 4; ++j) {
      int col = n0 + tx * 4 + j;
      float v = c[i][j] + bias[col];
      if (ACT == 1) v = fmaxf(v, 0.f);
      C[(size_t)row * Nc + col] = v;
    }
  }
}

// ---------------- fused QKV GEMM (same structure): A = out + pos; bf16 outputs ----------------
__global__ __launch_bounds__(128) void gemm_qkv_kernel(
    const float* __restrict__ outp, const float* __restrict__ pos,
    const float* __restrict__ Wq, const float* __restrict__ bq,
    const float* __restrict__ Wk, const float* __restrict__ bk,
    const float* __restrict__ Wv, const float* __restrict__ bv,
    unsigned short* __restrict__ Oq, unsigned short* __restrict__ Ok,
    unsigned short* __restrict__ Ov) {
  __shared__ float AsT[KCG][TM + 4];
  __shared__ float Bs[KCG][TN + 4];
  const int tid = threadIdx.x;
  const int tx = tid & 15;
  const int ty = tid >> 4;
  const int m0 = blockIdx.x * TM;
  const int wsel = blockIdx.y >> 2;
  const int n0 = (blockIdx.y & 3) * TN;
  const float* B = (wsel == 0) ? Wq : (wsel == 1) ? Wk : Wv;
  const float* bias = (wsel == 0) ? bq : (wsel == 1) ? bk : bv;
  unsigned short* C = (wsel == 0) ? Oq : (wsel == 1) ? Ok : Ov;

  float c[8][4] = {};

  for (int kc = 0; kc < D; kc += KCG) {
    {
      int r = tid >> 1;
      int gr = m0 + r;
      int kb = (tid & 1) * 32;
      const float* ar = outp + (size_t)gr * D + kc;
      const float* pr = pos + (size_t)(gr % Q) * D + kc;
#pragma unroll
      for (int q = 0; q < 8; ++q) {
        int k = kb + q * 4;
        float4 av = make_float4(0.f, 0.f, 0.f, 0.f);
        if (gr < NQ) {
          float4 ov = *(const float4*)(ar + k);
          float4 pv = *(const float4*)(pr + k);
          av.x = ov.x + pv.x; av.y = ov.y + pv.y; av.z = ov.z + pv.z; av.w = ov.w + pv.w;
        }
        AsT[k + 0][r] = av.x; AsT[k + 1][r] = av.y;
        AsT[k + 2][r] = av.z; AsT[k + 3][r] = av.w;
      }
    }
    {
#pragma unroll
      for (int i = 0; i < 8; ++i) {
        int idx = i * 128 + tid;
        int kr = idx >> 4;
        int c4 = (idx & 15) * 4;
        *(float4*)&Bs[kr][c4] = *(const float4*)(B + (size_t)(kc + kr) * D + n0 + c4);
      }
    }
    __syncthreads();
#pragma unroll 8
    for (int kk = 0; kk < KCG; ++kk) {
      float4 a0 = *(const float4*)&AsT[kk][ty * 8];
      float4 a1 = *(const float4*)&AsT[kk][ty * 8 + 4];
      float4 bv4 = *(const float4*)&Bs[kk][tx * 4];
      c[0][0] += a0.x * bv4.x; c[0][1] += a0.x * bv4.y; c[0][2] += a0.x * bv4.z; c[0][3] += a0.x * bv4.w;
      c[1][0] += a0.y * bv4.x; c[1][1] += a0.y * bv4.y; c[1][2] += a0.y * bv4.z; c[1][3] += a0.y * bv4.w;
      c[2][0] += a0.z * bv4.x; c[2][1] += a0.z * bv4.y; c[2][2] += a0.z * bv4.z; c[2][3] += a0.z * bv4.w;
      c[3][0] += a0.w * bv4.x; c[3][1] += a0.w * bv4.y; c[3][2] += a0.w * bv4.z; c[3][3] += a0.w * bv4.w;
      c[4][0] += a1.x * bv4.x; c[4][1] += a1.x * bv4.y; c[4][2] += a1.x * bv4.z; c[4][3] += a1.x * bv4.w;
      c[5][0] += a1.y * bv4.x; c[5][1] += a1.y * bv4.y; c[5][2] += a1.y * bv4.z; c[5][3] += a1.y * bv4.w;
      c[6][0] += a1.z * bv4.x; c[6][1] += a1.z * bv4.y; c[6][2] += a1.z * bv4.z; c[6][3] += a1.z * bv4.w;
      c[7][0] += a1.w * bv4.x; c[7][1] += a1.w * bv4.y; c[7][2] += a1.w * bv4.z; c[7][3] += a1.w * bv4.w;
    }
    __syncthreads();
  }

#pragma unroll
  for (int i = 0; i < 8; ++i) {
    int row = m0 + ty * 8 + i;
    if (row >= NQ) continue;
    ushort4 o4;
    o4.x = (unsigned short)bf16_of(c[i][0] + bias[n0 + tx * 4 + 0]);
    o4.y = (unsigned short)bf16_of(c[i][1] + bias[n0 + tx * 4 + 1]);
    o4.z = (unsigned short)bf16_of(c[i][2] + bias[n0 + tx * 4 + 2]);
    o4.w = (unsigned short)bf16_of(c[i][3] + bias[n0 + tx * 4 + 3]);
    *(ushort4*)(C + (size_t)row * D + n0 + tx * 4) = o4;
  }
}

// ---------------- thin slab GEMM (64x16, KC=128) for narrow outputs ----------------
#define TMT 64
#define KC 128
template <int ACT>
__global__ __launch_bounds__(256) void gemm_thin_kernel(
    const float* __restrict__ A, const float* __restrict__ B,
    const float* __restrict__ bias, float* __restrict__ C,
    int M, int K, int Nc) {
  __shared__ float AsT[KC][TMT + 4];
  __shared__ float Bs[KC][16 + 2];
  const int tid = threadIdx.x;
  const int tx = tid & 15, ty = tid >> 4;
  const int m0 = blockIdx.x * TMT, n0 = blockIdx.y * 16;

  float c[4] = {};

  for (int kc = 0; kc < K; kc += KC) {
    {
      int r = tid >> 2;
      int gr = m0 + r;
      int kb = (tid & 3) * 32;
#pragma unroll
      for (int q = 0; q < 8; ++q) {
        int k = kb + q * 4;
        float4 av = make_float4(0.f, 0.f, 0.f, 0.f);
        if (gr < M) av = *(const float4*)(A + (size_t)gr * K + kc + k);
        AsT[k + 0][r] = av.x; AsT[k + 1][r] = av.y;
        AsT[k + 2][r] = av.z; AsT[k + 3][r] = av.w;
      }
    }
    {
#pragma unroll
      for (int i = 0; i < 8; ++i) {
        int idx = i * 256 + tid;
        int kr = idx >> 4;
        int cc = idx & 15;
        int gc = n0 + cc;
        Bs[kr][cc] = (gc < Nc) ? B[(size_t)(kc + kr) * Nc + gc] : 0.f;
      }
    }
    __syncthreads();
#pragma unroll 8
    for (int kk = 0; kk < KC; ++kk) {
      float4 av = *(const float4*)&AsT[kk][ty * 4];
      float bv = Bs[kk][tx];
      c[0] += av.x * bv; c[1] += av.y * bv; c[2] += av.z * bv; c[3] += av.w * bv;
    }
    __syncthreads();
  }

  int col = n0 + tx;
  if (col < Nc) {
    float bs = bias[col];
#pragma unroll
    for (int i = 0; i < 4; ++i) {
      int row = m0 + ty * 4 + i;
      if (row < M) {
        float v = c[i] + bs;
        if (ACT == 2 && col < NCLS) v = 1.f / (1.f + expf(-v));
        C[(size_t)row * Nc + col] = v;
      }
    }
  }
}

// off (Nc=64, y 0..3) and aw (Nc=32, y 4..5) in one dispatch, KC=128 slabs
__global__ __launch_bounds__(256) void gemm_offaw_kernel(
    const float* __restrict__ A,
    const float* __restrict__ offW, const float* __restrict__ offb,
    const float* __restrict__ awW, const float* __restrict__ awb,
    float* __restrict__ offC, float* __restrict__ awC) {
  __shared__ float AsT[KC][TMT + 4];
  __shared__ float Bs[KC][16 + 2];
  const int tid = threadIdx.x;
  const int tx = tid & 15, ty = tid >> 4;
  const int m0 = blockIdx.x * TMT;
  const bool isOff = blockIdx.y < 4;
  const int n0 = isOff ? blockIdx.y * 16 : (blockIdx.y - 4) * 16;
  const int Nc = isOff ? 64 : 32;
  const float* B = isOff ? offW : awW;
  const float* bias = isOff ? offb : awb;
  float* C = isOff ? offC : awC;

  float c[4] = {};

  for (int kc = 0; kc < D; kc += KC) {
    {
      int r = tid >> 2;
      int gr = m0 + r;
      int kb = (tid & 3) * 32;
#pragma unroll
      for (int q = 0; q < 8; ++q) {
        int k = kb + q * 4;
        float4 av = make_float4(0.f, 0.f, 0.f, 0.f);
        if (gr < NQ) av = *(const float4*)(A + (size_t)gr * D + kc + k);
        AsT[k + 0][r] = av.x; AsT[k + 1][r] = av.y;
        AsT[k + 2][r] = av.z; AsT[k + 3][r] = av.w;
      }
    }
    {
#pragma unroll
      for (int i = 0; i < 8; ++i) {
        int idx = i * 256 + tid;
        int kr = idx >> 4;
        int cc = idx & 15;
        Bs[kr][cc] = B[(size_t)(kc + kr) * Nc + n0 + cc];
      }
    }
    __syncthreads();
#pragma unroll 8
    for (int kk = 0; kk < KC; ++kk) {
      float4 av = *(const float4*)&AsT[kk][ty * 4];
      float bv = Bs[kk][tx];
      c[0] += av.x * bv; c[1] += av.y * bv; c[2] += av.z * bv; c[3] += av.w * bv;
    }
    __syncthreads();
  }

  int col = n0 + tx;
  float bs = bias[col];
#pragma unroll
  for (int i = 0; i < 4; ++i) {
    int row = m0 + ty * 4 + i;
    if (row < NQ) C[(size_t)row * Nc + col] = c[i] + bs;
  }
}

// ---------------- MHA: MFMA flash attention, bf16 q/k/v; ONE WAVE per block ----------------
__global__ __launch_bounds__(64) void attn_kernel(
    const unsigned short* __restrict__ qg, const unsigned short* __restrict__ kg,
    const unsigned short* __restrict__ vg, float* __restrict__ og) {
  const int n = blockIdx.z, h = blockIdx.y;
  const int lane = threadIdx.x;     // 0..63
  const int g = lane >> 4;
  const int c = lane & 15;
  const int q0 = blockIdx.x * 16;

  const unsigned short* qb = qg + (size_t)n * Q * D + h * HD;
  const unsigned short* kb = kg + (size_t)n * Q * D + h * HD;
  const unsigned short* vb = vg + (size_t)n * Q * D + h * HD;

  short8v qf = {};
  {
    int qr = q0 + c;
    if (qr < Q) qf = *(const short8v*)(qb + (size_t)qr * D + g * 8);
  }

  const float SC2 = SCALE * 1.4426950408889634f;
  float m2 = -1e30f, l = 0.f;
  f32x4 acc0 = {0.f, 0.f, 0.f, 0.f}, acc1 = {0.f, 0.f, 0.f, 0.f};

  for (int kt0 = 0; kt0 < Q; kt0 += 64) {
    float s[16];
#pragma unroll
    for (int t = 0; t < 4; ++t) {
      short8v kf = {};
      int kr = kt0 + t * 16 + c;
      if (kr < Q) kf = *(const short8v*)(kb + (size_t)kr * D + g * 8);
      f32x4 d = __builtin_amdgcn_mfma_f32_16x16x32_bf16(kf, qf, (f32x4){0.f, 0.f, 0.f, 0.f}, 0, 0, 0);
#pragma unroll
      for (int r = 0; r < 4; ++r) s[t * 4 + r] = d[r];
    }
#pragma unroll
    for (int t = 0; t < 4; ++t)
#pragma unroll
      for (int r = 0; r < 4; ++r) {
        int key = kt0 + t * 16 + g * 4 + r;
        s[t * 4 + r] = (key < Q) ? s[t * 4 + r] * SC2 : -1e30f;
      }
    float tm = s[0];
#pragma unroll
    for (int j = 1; j < 16; ++j) tm = fmaxf(tm, s[j]);
    tm = fmaxf(tm, __shfl_xor(tm, 16));
    tm = fmaxf(tm, __shfl_xor(tm, 32));
    float m2n = fmaxf(m2, tm);
    float corr = exp2f(m2 - m2n);
    m2 = m2n;
    float ps = 0.f;
#pragma unroll
    for (int j = 0; j < 16; ++j) { s[j] = exp2f(s[j] - m2); ps += s[j]; }
    ps += __shfl_xor(ps, 16);
    ps += __shfl_xor(ps, 32);
    l = l * corr + ps;
    float cr0 = __shfl(corr, g * 4 + 0);
    float cr1 = __shfl(corr, g * 4 + 1);
    float cr2 = __shfl(corr, g * 4 + 2);
    float cr3 = __shfl(corr, g * 4 + 3);
    acc0[0] *= cr0; acc0[1] *= cr1; acc0[2] *= cr2; acc0[3] *= cr3;
    acc1[0] *= cr0; acc1[1] *= cr1; acc1[2] *= cr2; acc1[3] *= cr3;

#pragma unroll
    for (int pr = 0; pr < 2; ++pr) {
      short8v pa, v0 = {}, v1 = {};
#pragma unroll
      for (int j = 0; j < 8; ++j) pa[j] = bf16_of(s[pr * 8 + j]);
#pragma unroll
      for (int j = 0; j < 8; ++j) {
        int key = kt0 + (pr * 2 + (j >> 2)) * 16 + g * 4 + (j & 3);
        if (key < Q) {
          const unsigned short* vp = vb + (size_t)key * D;
          v0[j] = (short)vp[c];
          v1[j] = (short)vp[c + 16];
        }
      }
      acc0 = __builtin_amdgcn_mfma_f32_16x16x32_bf16(pa, v0, acc0, 0, 0, 0);
      acc1 = __builtin_amdgcn_mfma_f32_16x16x32_bf16(pa, v1, acc1, 0, 0, 0);
    }
  }

  float inv = 1.f / l;
  float iv[4];
#pragma unroll
  for (int r = 0; r < 4; ++r) iv[r] = __shfl(inv, g * 4 + r);
#pragma unroll
  for (int r = 0; r < 4; ++r) {
    int qr = q0 + g * 4 + r;
    if (qr < Q) {
      float* op = og + (size_t)(n * Q + qr) * D + h * HD;
      op[c] = acc0[r] * iv[r];
      op[c + 16] = acc1[r] * iv[r];
    }
  }
}

// ---------------- LayerNorm of (A + B): one wave per row ----------------
__global__ __launch_bounds__(256) void ln_add_kernel(
    const float* __restrict__ A, const float* __restrict__ Bp,
    const float* __restrict__ g, const float* __restrict__ b,
    float* __restrict__ out) {
  const int wave = threadIdx.x >> 6;
  const int lane = threadIdx.x & 63;
  const int row = blockIdx.x * 4 + wave;
  const size_t base = (size_t)row * D + lane * 4;
  float4 a4 = *(const float4*)(A + base);
  float4 b4 = *(const float4*)(Bp + base);
  float v0 = a4.x + b4.x, v1 = a4.y + b4.y, v2 = a4.z + b4.z, v3 = a4.w + b4.w;
  float sum = v0 + v1 + v2 + v3;
#pragma unroll
  for (int off = 1; off < 64; off <<= 1) sum += __shfl_xor(sum, off);
  float mean = sum * (1.f / D);
  float d0 = v0 - mean, d1 = v1 - mean, d2 = v2 - mean, d3 = v3 - mean;
  float vsum = d0 * d0 + d1 * d1 + d2 * d2 + d3 * d3;
#pragma unroll
  for (int off = 1; off < 64; off <<= 1) vsum += __shfl_xor(vsum, off);
  float inv_std = 1.0f / sqrtf(vsum * (1.f / D) + 1e-5f);
  float4 g4 = *(const float4*)(g + lane * 4);
  float4 bb4 = *(const float4*)(b + lane * 4);
  float4 o4;
  o4.x = d0 * inv_std * g4.x + bb4.x;
  o4.y = d1 * inv_std * g4.y + bb4.y;
  o4.z = d2 * inv_std * g4.z + bb4.z;
  o4.w = d3 * inv_std * g4.w + bb4.w;
  *(float4*)(out + base) = o4;
}

// ---------------- LayerNorm of (A + pos + B) ----------------
__global__ __launch_bounds__(256) void ln_add3_kernel(
    const float* __restrict__ A, const float* __restrict__ pos,
    const float* __restrict__ Bp,
    const float* __restrict__ g, const float* __restrict__ b,
    float* __restrict__ out) {
  const int wave = threadIdx.x >> 6;
  const int lane = threadIdx.x & 63;
  const int row = blockIdx.x * 4 + wave;
  const size_t base = (size_t)row * D + lane * 4;
  const size_t pbase = (size_t)(row % Q) * D + lane * 4;
  float4 a4 = *(const float4*)(A + base);
  float4 p4 = *(const float4*)(pos + pbase);
  float4 b4 = *(const float4*)(Bp + base);
  float x0 = a4.x + p4.x, x1 = a4.y + p4.y, x2 = a4.z + p4.z, x3 = a4.w + p4.w;
  float v0 = x0 + b4.x, v1 = x1 + b4.y, v2 = x2 + b4.z, v3 = x3 + b4.w;
  float sum = v0 + v1 + v2 + v3;
#pragma unroll
  for (int off = 1; off < 64; off <<= 1) sum += __shfl_xor(sum, off);
  float mean = sum * (1.f / D);
  float d0 = v0 - mean, d1 = v1 - mean, d2 = v2 - mean, d3 = v3 - mean;
  float vsum = d0 * d0 + d1 * d1 + d2 * d2 + d3 * d3;
#pragma unroll
  for (int off = 1; off < 64; off <<= 1) vsum += __shfl_xor(vsum, off);
  float inv_std = 1.0f / sqrtf(vsum * (1.f / D) + 1e-5f);
  float4 g4 = *(const float4*)(g + lane * 4);
  float4 bb4 = *(const float4*)(b + lane * 4);
  float4 o4;
  o4.x = d0 * inv_std * g4.x + bb4.x;
  o4.y = d1 * inv_std * g4.y + bb4.y;
  o4.z = d2 * inv_std * g4.z + bb4.z;
  o4.w = d3 * inv_std * g4.w + bb4.w;
  *(float4*)(out + base) = o4;
}

// ---------------- deformable attention v4: 4 queries per block (fused, verified) ----------------
__global__ __launch_bounds__(256) void deform_kernel(
    const float* __restrict__ bev, const float* __restrict__ offB,
    const float* __restrict__ awB, const float* __restrict__ dvW,
    const float* __restrict__ dvb, float* __restrict__ dtmp) {
  const int bq0 = blockIdx.x * 4;
  const int n = bq0 / Q;
  const int t = threadIdx.x;

  __shared__ float aw_s[4][NH * P];
  __shared__ int   idx_s[4][NH * P * 4];
  __shared__ float w_s[4][NH * P * 4];
  __shared__ float agg_s[4][NH][D];
  __shared__ float red_s[4][4][D];

  if (t < 128) {
    int qq = t >> 5, e = t & 31;
    int bq = bq0 + qq;
    int qi = bq - n * Q;
    // reference point: XLA f32 linspace, reciprocal-multiply delta (verified)
    float tq = __fmul_rn((float)qi, 44.492767333984375f);
    int ir = (int)rintf(tq);
    float rx = (float)(ir % WB);
    float ry = (float)(ir / WB);
    float ox = offB[(size_t)bq * 64 + e * 2 + 0];
    float oy = offB[(size_t)bq * 64 + e * 2 + 1];
    float lx = fminf(fmaxf(rx + ox, 0.f), (float)(WB - 1));
    float ly = fminf(fmaxf(ry + oy, 0.f), (float)(HB - 1));
    float x0 = floorf(lx), y0 = floorf(ly);
    float x1 = fminf(x0 + 1.f, (float)(WB - 1));
    float y1 = fminf(y0 + 1.f, (float)(HB - 1));
    float wx = lx - x0, wy = ly - y0;
    int b4 = e * 4;
    idx_s[qq][b4 + 0] = (int)y0 * WB + (int)x0; w_s[qq][b4 + 0] = (1.f - wx) * (1.f - wy);
    idx_s[qq][b4 + 1] = (int)y0 * WB + (int)x1; w_s[qq][b4 + 1] = wx * (1.f - wy);
    idx_s[qq][b4 + 2] = (int)y1 * WB + (int)x0; w_s[qq][b4 + 2] = (1.f - wx) * wy;
    idx_s[qq][b4 + 3] = (int)y1 * WB + (int)x1; w_s[qq][b4 + 3] = wx * wy;
  } else if (t < 160) {
    int idx = t - 128;
    int qq = idx >> 3, hh = idx & 7;
    const float* ap = awB + (size_t)(bq0 + qq) * 32 + hh * P;
    float l0 = ap[0], l1 = ap[1], l2 = ap[2], l3 = ap[3];
    float mx = fmaxf(fmaxf(l0, l1), fmaxf(l2, l3));
    float e0 = expf(l0 - mx), e1 = expf(l1 - mx), e2 = expf(l2 - mx), e3 = expf(l3 - mx);
    float inv = 1.f / (e0 + e1 + e2 + e3);
    aw_s[qq][hh * P + 0] = e0 * inv; aw_s[qq][hh * P + 1] = e1 * inv;
    aw_s[qq][hh * P + 2] = e2 * inv; aw_s[qq][hh * P + 3] = e3 * inv;
  }
  __syncthreads();

  {
    const float* bevn = bev + (size_t)n * HW * D;
    const int wv = t >> 6, lane = t & 63;
    const int c4 = lane * 4;
#pragma unroll
    for (int u = 0; u < 8; ++u) {
      int pid = wv + u * 4;
      int qq = pid >> 3, h = pid & 7;
      f32x4 acc = {0.f, 0.f, 0.f, 0.f};
#pragma unroll
      for (int p = 0; p < P; ++p) {
        int e = h * P + p;
        float aw = aw_s[qq][e];
        const int* ix = &idx_s[qq][e * 4];
        const float* wsp = &w_s[qq][e * 4];
        float4 g0 = *(const float4*)(bevn + (size_t)ix[0] * D + c4);
        float4 g1 = *(const float4*)(bevn + (size_t)ix[1] * D + c4);
        float4 g2 = *(const float4*)(bevn + (size_t)ix[2] * D + c4);
        float4 g3 = *(const float4*)(bevn + (size_t)ix[3] * D + c4);
        acc[0] += aw * (wsp[0] * g0.x + wsp[1] * g1.x + wsp[2] * g2.x + wsp[3] * g3.x);
        acc[1] += aw * (wsp[0] * g0.y + wsp[1] * g1.y + wsp[2] * g2.y + wsp[3] * g3.y);
        acc[2] += aw * (wsp[0] * g0.z + wsp[1] * g1.z + wsp[2] * g2.z + wsp[3] * g3.z);
        acc[3] += aw * (wsp[0] * g0.w + wsp[1] * g1.w + wsp[2] * g2.w + wsp[3] * g3.w);
      }
      *(f32x4*)&agg_s[qq][h][c4] = acc;
    }
  }
  __syncthreads();

  {
    const int chunk = t >> 6;
    const int col4 = t & 63;
    const int tt0 = col4 * 4;
    const int h = tt0 >> 5;
    f32x4 p[4] = {{0.f,0.f,0.f,0.f},{0.f,0.f,0.f,0.f},{0.f,0.f,0.f,0.f},{0.f,0.f,0.f,0.f}};
#pragma unroll 4
    for (int dd4 = 0; dd4 < 64; dd4 += 4) {
      int dd = chunk * 64 + dd4;
      float4 w0 = *(const float4*)(dvW + (size_t)(dd + 0) * D + tt0);
      float4 w1 = *(const float4*)(dvW + (size_t)(dd + 1) * D + tt0);
      float4 w2 = *(const float4*)(dvW + (size_t)(dd + 2) * D + tt0);
      float4 w3 = *(const float4*)(dvW + (size_t)(dd + 3) * D + tt0);
#pragma unroll
      for (int qq = 0; qq < 4; ++qq) {
        float4 a = *(const float4*)&agg_s[qq][h][dd];
        p[qq][0] += a.x * w0.x + a.y * w1.x + a.z * w2.x + a.w * w3.x;
        p[qq][1] += a.x * w0.y + a.y * w1.y + a.z * w2.y + a.w * w3.y;
        p[qq][2] += a.x * w0.z + a.y * w1.z + a.z * w2.z + a.w * w3.z;
        p[qq][3] += a.x * w0.w + a.y * w1.w + a.z * w2.w + a.w * w3.w;
      }
    }
#pragma unroll
    for (int qq = 0; qq < 4; ++qq) *(f32x4*)&red_s[qq][chunk][tt0] = p[qq];
  }
  __syncthreads();
  {
    float bs = dvb[t];
#pragma unroll
    for (int qq = 0; qq < 4; ++qq) {
      dtmp[(size_t)(bq0 + qq) * D + t] =
          bs + red_s[qq][0][t] + red_s[qq][1][t] + red_s[qq][2][t] + red_s[qq][3][t];
    }
  }
}

// ---------------- small elementwise kernels ----------------
__global__ void bcast_q_kernel(const float* __restrict__ pos, float* __restrict__ out) {
  for (size_t i = (size_t)blockIdx.x * blockDim.x + threadIdx.x; i < (size_t)NQD;
       i += (size_t)gridDim.x * blockDim.x)
    out[i] = pos[i % QD];
}
__global__ void finalize_kernel(const float* __restrict__ lr5, float* __restrict__ det,
                                float* __restrict__ mask) {
  int i = blockIdx.x * blockDim.x + threadIdx.x;
  if (i < NQ * ODIM) det[i] = lr5[i];
  if (i < NQ) mask[i] = (lr5[(size_t)i * ODIM] >= 0.5f) ? 1.0f : 0.0f;
}

// ---------------- host ----------------
extern "C" void kernel_launch(void* const* d_in, const int* in_sizes, int n_in,
                              void* d_out, int out_size, void* d_ws, size_t ws_size,
                              hipStream_t stream) {
  const float* bev  = (const float*)d_in[0];
  const float* pos  = (const float*)d_in[1];
  const float* Wq   = (const float*)d_in[2];  const float* bq  = (const float*)d_in[3];
  const float* Wk   = (const float*)d_in[4];  const float* bk  = (const float*)d_in[5];
  const float* Wv   = (const float*)d_in[6];  const float* bv  = (const float*)d_in[7];
  const float* Wo   = (const float*)d_in[8];  const float* bo  = (const float*)d_in[9];
  const float* ln1g = (const float*)d_in[10]; const float* ln1b = (const float*)d_in[11];
  const float* ln2g = (const float*)d_in[12]; const float* ln2b = (const float*)d_in[13];
  const float* ln3g = (const float*)d_in[14]; const float* ln3b = (const float*)d_in[15];
  const float* dvW  = (const float*)d_in[16]; const float* dvb = (const float*)d_in[17];
  const float* offW = (const float*)d_in[18]; const float* offb = (const float*)d_in[19];
  const float* awW  = (const float*)d_in[20]; const float* awb = (const float*)d_in[21];
  const float* doW  = (const float*)d_in[22]; const float* dob = (const float*)d_in[23];
  const float* f1W  = (const float*)d_in[24]; const float* f1b = (const float*)d_in[25];
  const float* f2W  = (const float*)d_in[26]; const float* f2b = (const float*)d_in[27];
  const float* dW1  = (const float*)d_in[28]; const float* db1 = (const float*)d_in[29];
  const float* dW2  = (const float*)d_in[30]; const float* db2 = (const float*)d_in[31];

  float* w = (float*)d_ws;
  float* b0 = w + 0 * (size_t)NQD;   // o -> offB/awB -> x3
  float* b1 = w + 1 * (size_t)NQD;   // q/k bf16 -> a -> d -> ffh(lo) -> deth
  float* b2 = w + 2 * (size_t)NQD;   // v bf16 -> x2 -> ffh(hi)
  float* b3 = w + 3 * (size_t)NQD;   // dtmp -> f
  float* ffh = b1;                   // spans b1..b2
  float* offB = b0;                  // NQ*64
  float* awB  = b0 + (size_t)NQ * 64;
  unsigned short* qb16 = (unsigned short*)b1;
  unsigned short* kb16 = (unsigned short*)b1 + NQD;
  unsigned short* vb16 = (unsigned short*)b2;

  float* out_output = (float*)d_out;
  float* out_det    = out_output + (size_t)NQD;
  float* out_mask   = out_det + (size_t)NQ * ODIM;
  float* out_lr     = out_mask + (size_t)NQ;

  const dim3 blk256(256);
  const dim3 blk128(128);
  const dim3 blk64(64);
  const dim3 qkvGrid((NQ + TM - 1) / TM, 12);
  const dim3 gemmGridD((NQ + TM - 1) / TM, D / TN);
  const dim3 gemmGridFF((NQ + TM - 1) / TM, FF / TN);
  const dim3 offawGrid((NQ + TMT - 1) / TMT, 6);
  const dim3 thinGridDet((NQ + TMT - 1) / TMT, 2);
  const dim3 attnGrid((Q + 15) / 16, NH, N);     // 57 x 8 x 8 one-wave blocks
  const dim3 lnGrid(NQ / 4);
  const dim3 defGrid(NQ / 4);
  const int ewGrid = 1024;

  bcast_q_kernel<<<ewGrid, blk256, 0, stream>>>(pos, out_output);

  for (int i = 0; i < L; ++i) {
    const size_t wDD = (size_t)i * D * D;
    // q,k,v (bf16 outputs; A = output + pos computed on the fly)
    gemm_qkv_kernel<<<qkvGrid, blk128, 0, stream>>>(out_output, pos,
        Wq + wDD, bq + (size_t)i * D, Wk + wDD, bk + (size_t)i * D,
        Wv + wDD, bv + (size_t)i * D, qb16, kb16, vb16);
    // attention -> o (b0)
    attn_kernel<<<attnGrid, blk64, 0, stream>>>(qb16, kb16, vb16, b0);
    // a = o @ Wo + bo -> b1 (q/k bf16 dead)
    gemm_kernel<0><<<gemmGridD, blk128, 0, stream>>>(b0, Wo + wDD, bo + (size_t)i * D, b1, NQ, D, D);
    // x2 = LN1(output + pos + a) -> b2 (v bf16 dead)
    ln_add3_kernel<<<lnGrid, blk256, 0, stream>>>(out_output, pos, b1,
        ln1g + (size_t)i * D, ln1b + (size_t)i * D, b2);
    // off + aw logits -> offB/awB (b0; o dead)
    gemm_offaw_kernel<<<offawGrid, blk256, 0, stream>>>(b2,
        offW + (size_t)i * D * 64, offb + (size_t)i * 64,
        awW + (size_t)i * D * 32, awb + (size_t)i * 32, offB, awB);
    // deform (fused, 4 queries/block) -> b3
    deform_kernel<<<defGrid, blk256, 0, stream>>>(bev, offB, awB, dvW + wDD, dvb + (size_t)i * D, b3);
    // d = dtmp @ do_W + do_b -> b1
    gemm_kernel<0><<<gemmGridD, blk128, 0, stream>>>(b3, doW + wDD, dob + (size_t)i * D, b1, NQ, D, D);
    // x3 = LN2(x2 + d) -> b0
    ln_add_kernel<<<lnGrid, blk256, 0, stream>>>(b2, b1, ln2g + (size_t)i * D, ln2b + (size_t)i * D, b0);
    // FFN
    gemm_kernel<1><<<gemmGridFF, blk128, 0, stream>>>(b0, f1W + (size_t)i * D * FF, f1b + (size_t)i * FF, ffh, NQ, D, FF);
    gemm_kernel<0><<<gemmGridD, blk128, 0, stream>>>(ffh, f2W + (size_t)i * FF * D, f2b + (size_t)i * D, b3, NQ, FF, D);
    // output = LN3(x3 + f) -> out_output
    ln_add_kernel<<<lnGrid, blk256, 0, stream>>>(b0, b3, ln3g + (size_t)i * D, ln3b + (size_t)i * D, out_output);
    // det head
    gemm_kernel<1><<<gemmGridD, blk128, 0, stream>>>(out_output, dW1, db1, b1, NQ, D, D);
    gemm_thin_kernel<2><<<thinGridDet, blk256, 0, stream>>>(b1, dW2, db2, out_lr + (size_t)i * NQ * ODIM, NQ, D, ODIM);
  }

  finalize_kernel<<<(NQ * ODIM + 255) / 256, blk256, 0, stream>>>(out_lr + (size_t)(L - 1) * NQ * ODIM,
                                                                  out_det, out_mask);
}

// Round 19
// 2401.945 us; speedup vs baseline: 1.1201x; 1.1201x over previous
//
#include <hip/hip_runtime.h>
#include <hip/hip_bf16.h>
#include <math.h>

#define N 8
#define Q 900
#define D 256
#define HB 200
#define WB 200
#define L 6
#define NH 8
#define P 4
#define HD 32
#define FF 512
#define NCLS 10
#define ODIM 18
#define HW (HB*WB)
#define NQ (N*Q)
#define NQD (NQ*D)
#define QD (Q*D)
#define SCALE 0.17677669529663687f

typedef __attribute__((ext_vector_type(4))) float f32x4;
typedef __attribute__((ext_vector_type(8))) short short8v;

__device__ __forceinline__ short bf16_of(float f) {
  __hip_bfloat16 h = __float2bfloat16(f);
  return __builtin_bit_cast(short, h);
}

// ---------------- slab-staged f32 GEMM, 64x64 tile, K-chunks of 128 ----------------
// ACT: 0 = none, 1 = relu
#define TM 64
#define TN 64
#define KC 128

template <int ACT>
__global__ __launch_bounds__(256) void gemm_kernel(
    const float* __restrict__ A, const float* __restrict__ B,
    const float* __restrict__ bias, float* __restrict__ C,
    int M, int K, int Nc) {
  __shared__ float AsT[KC][TM + 4];
  __shared__ float Bs[KC][TN + 4];
  const int tid = threadIdx.x;
  const int tx = tid & 15, ty = tid >> 4;
  const int m0 = blockIdx.x * TM, n0 = blockIdx.y * TN;

  float c[4][4] = {};

  for (int kc = 0; kc < K; kc += KC) {
    {
      int r = tid >> 2;
      int gr = m0 + r;
      int kb = (tid & 3) * 32;
#pragma unroll
      for (int q = 0; q < 8; ++q) {
        int k = kb + q * 4;
        float4 av = make_float4(0.f, 0.f, 0.f, 0.f);
        if (gr < M) av = *(const float4*)(A + (size_t)gr * K + kc + k);
        AsT[k + 0][r] = av.x; AsT[k + 1][r] = av.y;
        AsT[k + 2][r] = av.z; AsT[k + 3][r] = av.w;
      }
    }
    {
#pragma unroll
      for (int i = 0; i < 8; ++i) {
        int idx = i * 256 + tid;
        int kr = idx >> 4;
        int c4 = (idx & 15) * 4;
        *(float4*)&Bs[kr][c4] = *(const float4*)(B + (size_t)(kc + kr) * Nc + n0 + c4);
      }
    }
    __syncthreads();
#pragma unroll 8
    for (int kk = 0; kk < KC; ++kk) {
      float4 av = *(const float4*)&AsT[kk][ty * 4];
      float4 bv = *(const float4*)&Bs[kk][tx * 4];
      c[0][0] += av.x * bv.x; c[0][1] += av.x * bv.y; c[0][2] += av.x * bv.z; c[0][3] += av.x * bv.w;
      c[1][0] += av.y * bv.x; c[1][1] += av.y * bv.y; c[1][2] += av.y * bv.z; c[1][3] += av.y * bv.w;
      c[2][0] += av.z * bv.x; c[2][1] += av.z * bv.y; c[2][2] += av.z * bv.z; c[2][3] += av.z * bv.w;
      c[3][0] += av.w * bv.x; c[3][1] += av.w * bv.y; c[3][2] += av.w * bv.z; c[3][3] += av.w * bv.w;
    }
    __syncthreads();
  }

#pragma unroll
  for (int i = 0; i < 4; ++i) {
    int row = m0 + ty * 4 + i;
    if (row >= M) continue;
#pragma unroll
    for (int j = 0; j < 4; ++j) {
      int col = n0 + tx * 4 + j;
      float v = c[i][j] + bias[col];
      if (ACT == 1) v = fmaxf(v, 0.f);
      C[(size_t)row * Nc + col] = v;
    }
  }
}

// ---------------- fused QKV GEMM: A = out + pos on the fly; bf16 outputs ----------------
__global__ __launch_bounds__(256) void gemm_qkv_kernel(
    const float* __restrict__ outp, const float* __restrict__ pos,
    const float* __restrict__ Wq, const float* __restrict__ bq,
    const float* __restrict__ Wk, const float* __restrict__ bk,
    const float* __restrict__ Wv, const float* __restrict__ bv,
    unsigned short* __restrict__ Oq, unsigned short* __restrict__ Ok,
    unsigned short* __restrict__ Ov) {
  __shared__ float AsT[KC][TM + 4];
  __shared__ float Bs[KC][TN + 4];
  const int tid = threadIdx.x;
  const int tx = tid & 15, ty = tid >> 4;
  const int m0 = blockIdx.x * TM;
  const int wsel = blockIdx.y >> 2;
  const int n0 = (blockIdx.y & 3) * TN;
  const float* B = (wsel == 0) ? Wq : (wsel == 1) ? Wk : Wv;
  const float* bias = (wsel == 0) ? bq : (wsel == 1) ? bk : bv;
  unsigned short* C = (wsel == 0) ? Oq : (wsel == 1) ? Ok : Ov;

  float c[4][4] = {};

  for (int kc = 0; kc < D; kc += KC) {
    {
      int r = tid >> 2;
      int gr = m0 + r;
      int kb = (tid & 3) * 32;
      const float* ar = outp + (size_t)gr * D + kc;
      const float* pr = pos + (size_t)(gr % Q) * D + kc;
#pragma unroll
      for (int q = 0; q < 8; ++q) {
        int k = kb + q * 4;
        float4 av = make_float4(0.f, 0.f, 0.f, 0.f);
        if (gr < NQ) {
          float4 ov = *(const float4*)(ar + k);
          float4 pv = *(const float4*)(pr + k);
          av.x = ov.x + pv.x; av.y = ov.y + pv.y; av.z = ov.z + pv.z; av.w = ov.w + pv.w;
        }
        AsT[k + 0][r] = av.x; AsT[k + 1][r] = av.y;
        AsT[k + 2][r] = av.z; AsT[k + 3][r] = av.w;
      }
    }
    {
#pragma unroll
      for (int i = 0; i < 8; ++i) {
        int idx = i * 256 + tid;
        int kr = idx >> 4;
        int c4 = (idx & 15) * 4;
        *(float4*)&Bs[kr][c4] = *(const float4*)(B + (size_t)(kc + kr) * D + n0 + c4);
      }
    }
    __syncthreads();
#pragma unroll 8
    for (int kk = 0; kk < KC; ++kk) {
      float4 av = *(const float4*)&AsT[kk][ty * 4];
      float4 bv4 = *(const float4*)&Bs[kk][tx * 4];
      c[0][0] += av.x * bv4.x; c[0][1] += av.x * bv4.y; c[0][2] += av.x * bv4.z; c[0][3] += av.x * bv4.w;
      c[1][0] += av.y * bv4.x; c[1][1] += av.y * bv4.y; c[1][2] += av.y * bv4.z; c[1][3] += av.y * bv4.w;
      c[2][0] += av.z * bv4.x; c[2][1] += av.z * bv4.y; c[2][2] += av.z * bv4.z; c[2][3] += av.z * bv4.w;
      c[3][0] += av.w * bv4.x; c[3][1] += av.w * bv4.y; c[3][2] += av.w * bv4.z; c[3][3] += av.w * bv4.w;
    }
    __syncthreads();
  }

#pragma unroll
  for (int i = 0; i < 4; ++i) {
    int row = m0 + ty * 4 + i;
    if (row >= NQ) continue;
    ushort4 o4;
    o4.x = (unsigned short)bf16_of(c[i][0] + bias[n0 + tx * 4 + 0]);
    o4.y = (unsigned short)bf16_of(c[i][1] + bias[n0 + tx * 4 + 1]);
    o4.z = (unsigned short)bf16_of(c[i][2] + bias[n0 + tx * 4 + 2]);
    o4.w = (unsigned short)bf16_of(c[i][3] + bias[n0 + tx * 4 + 3]);
    *(ushort4*)(C + (size_t)row * D + n0 + tx * 4) = o4;
  }
}

// ---------------- thin slab GEMM (64x16, KC=128) for narrow outputs ----------------
#define TMT 64
template <int ACT>
__global__ __launch_bounds__(256) void gemm_thin_kernel(
    const float* __restrict__ A, const float* __restrict__ B,
    const float* __restrict__ bias, float* __restrict__ C,
    int M, int K, int Nc) {
  __shared__ float AsT[KC][TMT + 4];
  __shared__ float Bs[KC][16 + 2];
  const int tid = threadIdx.x;
  const int tx = tid & 15, ty = tid >> 4;
  const int m0 = blockIdx.x * TMT, n0 = blockIdx.y * 16;

  float c[4] = {};

  for (int kc = 0; kc < K; kc += KC) {
    {
      int r = tid >> 2;
      int gr = m0 + r;
      int kb = (tid & 3) * 32;
#pragma unroll
      for (int q = 0; q < 8; ++q) {
        int k = kb + q * 4;
        float4 av = make_float4(0.f, 0.f, 0.f, 0.f);
        if (gr < M) av = *(const float4*)(A + (size_t)gr * K + kc + k);
        AsT[k + 0][r] = av.x; AsT[k + 1][r] = av.y;
        AsT[k + 2][r] = av.z; AsT[k + 3][r] = av.w;
      }
    }
    {
#pragma unroll
      for (int i = 0; i < 8; ++i) {
        int idx = i * 256 + tid;
        int kr = idx >> 4;
        int cc = idx & 15;
        int gc = n0 + cc;
        Bs[kr][cc] = (gc < Nc) ? B[(size_t)(kc + kr) * Nc + gc] : 0.f;
      }
    }
    __syncthreads();
#pragma unroll 8
    for (int kk = 0; kk < KC; ++kk) {
      float4 av = *(const float4*)&AsT[kk][ty * 4];
      float bv = Bs[kk][tx];
      c[0] += av.x * bv; c[1] += av.y * bv; c[2] += av.z * bv; c[3] += av.w * bv;
    }
    __syncthreads();
  }

  int col = n0 + tx;
  if (col < Nc) {
    float bs = bias[col];
#pragma unroll
    for (int i = 0; i < 4; ++i) {
      int row = m0 + ty * 4 + i;
      if (row < M) {
        float v = c[i] + bs;
        if (ACT == 2 && col < NCLS) v = 1.f / (1.f + expf(-v));
        C[(size_t)row * Nc + col] = v;
      }
    }
  }
}

// off (Nc=64, y 0..3) and aw (Nc=32, y 4..5) in one dispatch, KC=128 slabs
__global__ __launch_bounds__(256) void gemm_offaw_kernel(
    const float* __restrict__ A,
    const float* __restrict__ offW, const float* __restrict__ offb,
    const float* __restrict__ awW, const float* __restrict__ awb,
    float* __restrict__ offC, float* __restrict__ awC) {
  __shared__ float AsT[KC][TMT + 4];
  __shared__ float Bs[KC][16 + 2];
  const int tid = threadIdx.x;
  const int tx = tid & 15, ty = tid >> 4;
  const int m0 = blockIdx.x * TMT;
  const bool isOff = blockIdx.y < 4;
  const int n0 = isOff ? blockIdx.y * 16 : (blockIdx.y - 4) * 16;
  const int Nc = isOff ? 64 : 32;
  const float* B = isOff ? offW : awW;
  const float* bias = isOff ? offb : awb;
  float* C = isOff ? offC : awC;

  float c[4] = {};

  for (int kc = 0; kc < D; kc += KC) {
    {
      int r = tid >> 2;
      int gr = m0 + r;
      int kb = (tid & 3) * 32;
#pragma unroll
      for (int q = 0; q < 8; ++q) {
        int k = kb + q * 4;
        float4 av = make_float4(0.f, 0.f, 0.f, 0.f);
        if (gr < NQ) av = *(const float4*)(A + (size_t)gr * D + kc + k);
        AsT[k + 0][r] = av.x; AsT[k + 1][r] = av.y;
        AsT[k + 2][r] = av.z; AsT[k + 3][r] = av.w;
      }
    }
    {
#pragma unroll
      for (int i = 0; i < 8; ++i) {
        int idx = i * 256 + tid;
        int kr = idx >> 4;
        int cc = idx & 15;
        Bs[kr][cc] = B[(size_t)(kc + kr) * Nc + n0 + cc];
      }
    }
    __syncthreads();
#pragma unroll 8
    for (int kk = 0; kk < KC; ++kk) {
      float4 av = *(const float4*)&AsT[kk][ty * 4];
      float bv = Bs[kk][tx];
      c[0] += av.x * bv; c[1] += av.y * bv; c[2] += av.z * bv; c[3] += av.w * bv;
    }
    __syncthreads();
  }

  int col = n0 + tx;
  float bs = bias[col];
#pragma unroll
  for (int i = 0; i < 4; ++i) {
    int row = m0 + ty * 4 + i;
    if (row < NQ) C[(size_t)row * Nc + col] = c[i] + bs;
  }
}

// ---------------- MHA: MFMA flash attention, bf16 q/k/v; ONE WAVE per block ----------------
__global__ __launch_bounds__(64) void attn_kernel(
    const unsigned short* __restrict__ qg, const unsigned short* __restrict__ kg,
    const unsigned short* __restrict__ vg, float* __restrict__ og) {
  const int n = blockIdx.z, h = blockIdx.y;
  const int lane = threadIdx.x;     // 0..63
  const int g = lane >> 4;
  const int c = lane & 15;
  const int q0 = blockIdx.x * 16;

  const unsigned short* qb = qg + (size_t)n * Q * D + h * HD;
  const unsigned short* kb = kg + (size_t)n * Q * D + h * HD;
  const unsigned short* vb = vg + (size_t)n * Q * D + h * HD;

  short8v qf = {};
  {
    int qr = q0 + c;
    if (qr < Q) qf = *(const short8v*)(qb + (size_t)qr * D + g * 8);
  }

  const float SC2 = SCALE * 1.4426950408889634f;
  float m2 = -1e30f, l = 0.f;
  f32x4 acc0 = {0.f, 0.f, 0.f, 0.f}, acc1 = {0.f, 0.f, 0.f, 0.f};

  for (int kt0 = 0; kt0 < Q; kt0 += 64) {
    float s[16];
#pragma unroll
    for (int t = 0; t < 4; ++t) {
      short8v kf = {};
      int kr = kt0 + t * 16 + c;
      if (kr < Q) kf = *(const short8v*)(kb + (size_t)kr * D + g * 8);
      f32x4 d = __builtin_amdgcn_mfma_f32_16x16x32_bf16(kf, qf, (f32x4){0.f, 0.f, 0.f, 0.f}, 0, 0, 0);
#pragma unroll
      for (int r = 0; r < 4; ++r) s[t * 4 + r] = d[r];
    }
#pragma unroll
    for (int t = 0; t < 4; ++t)
#pragma unroll
      for (int r = 0; r < 4; ++r) {
        int key = kt0 + t * 16 + g * 4 + r;
        s[t * 4 + r] = (key < Q) ? s[t * 4 + r] * SC2 : -1e30f;
      }
    float tm = s[0];
#pragma unroll
    for (int j = 1; j < 16; ++j) tm = fmaxf(tm, s[j]);
    tm = fmaxf(tm, __shfl_xor(tm, 16));
    tm = fmaxf(tm, __shfl_xor(tm, 32));
    float m2n = fmaxf(m2, tm);
    float corr = exp2f(m2 - m2n);
    m2 = m2n;
    float ps = 0.f;
#pragma unroll
    for (int j = 0; j < 16; ++j) { s[j] = exp2f(s[j] - m2); ps += s[j]; }
    ps += __shfl_xor(ps, 16);
    ps += __shfl_xor(ps, 32);
    l = l * corr + ps;
    float cr0 = __shfl(corr, g * 4 + 0);
    float cr1 = __shfl(corr, g * 4 + 1);
    float cr2 = __shfl(corr, g * 4 + 2);
    float cr3 = __shfl(corr, g * 4 + 3);
    acc0[0] *= cr0; acc0[1] *= cr1; acc0[2] *= cr2; acc0[3] *= cr3;
    acc1[0] *= cr0; acc1[1] *= cr1; acc1[2] *= cr2; acc1[3] *= cr3;

#pragma unroll
    for (int pr = 0; pr < 2; ++pr) {
      short8v pa, v0 = {}, v1 = {};
#pragma unroll
      for (int j = 0; j < 8; ++j) pa[j] = bf16_of(s[pr * 8 + j]);
#pragma unroll
      for (int j = 0; j < 8; ++j) {
        int key = kt0 + (pr * 2 + (j >> 2)) * 16 + g * 4 + (j & 3);
        if (key < Q) {
          const unsigned short* vp = vb + (size_t)key * D;
          v0[j] = (short)vp[c];
          v1[j] = (short)vp[c + 16];
        }
      }
      acc0 = __builtin_amdgcn_mfma_f32_16x16x32_bf16(pa, v0, acc0, 0, 0, 0);
      acc1 = __builtin_amdgcn_mfma_f32_16x16x32_bf16(pa, v1, acc1, 0, 0, 0);
    }
  }

  float inv = 1.f / l;
  float iv[4];
#pragma unroll
  for (int r = 0; r < 4; ++r) iv[r] = __shfl(inv, g * 4 + r);
#pragma unroll
  for (int r = 0; r < 4; ++r) {
    int qr = q0 + g * 4 + r;
    if (qr < Q) {
      float* op = og + (size_t)(n * Q + qr) * D + h * HD;
      op[c] = acc0[r] * iv[r];
      op[c + 16] = acc1[r] * iv[r];
    }
  }
}

// ---------------- LayerNorm of (A + B): one wave per row ----------------
__global__ __launch_bounds__(256) void ln_add_kernel(
    const float* __restrict__ A, const float* __restrict__ Bp,
    const float* __restrict__ g, const float* __restrict__ b,
    float* __restrict__ out) {
  const int wave = threadIdx.x >> 6;
  const int lane = threadIdx.x & 63;
  const int row = blockIdx.x * 4 + wave;
  const size_t base = (size_t)row * D + lane * 4;
  float4 a4 = *(const float4*)(A + base);
  float4 b4 = *(const float4*)(Bp + base);
  float v0 = a4.x + b4.x, v1 = a4.y + b4.y, v2 = a4.z + b4.z, v3 = a4.w + b4.w;
  float sum = v0 + v1 + v2 + v3;
#pragma unroll
  for (int off = 1; off < 64; off <<= 1) sum += __shfl_xor(sum, off);
  float mean = sum * (1.f / D);
  float d0 = v0 - mean, d1 = v1 - mean, d2 = v2 - mean, d3 = v3 - mean;
  float vsum = d0 * d0 + d1 * d1 + d2 * d2 + d3 * d3;
#pragma unroll
  for (int off = 1; off < 64; off <<= 1) vsum += __shfl_xor(vsum, off);
  float inv_std = 1.0f / sqrtf(vsum * (1.f / D) + 1e-5f);
  float4 g4 = *(const float4*)(g + lane * 4);
  float4 bb4 = *(const float4*)(b + lane * 4);
  float4 o4;
  o4.x = d0 * inv_std * g4.x + bb4.x;
  o4.y = d1 * inv_std * g4.y + bb4.y;
  o4.z = d2 * inv_std * g4.z + bb4.z;
  o4.w = d3 * inv_std * g4.w + bb4.w;
  *(float4*)(out + base) = o4;
}

// ---------------- LayerNorm of (A + pos + B) ----------------
__global__ __launch_bounds__(256) void ln_add3_kernel(
    const float* __restrict__ A, const float* __restrict__ pos,
    const float* __restrict__ Bp,
    const float* __restrict__ g, const float* __restrict__ b,
    float* __restrict__ out) {
  const int wave = threadIdx.x >> 6;
  const int lane = threadIdx.x & 63;
  const int row = blockIdx.x * 4 + wave;
  const size_t base = (size_t)row * D + lane * 4;
  const size_t pbase = (size_t)(row % Q) * D + lane * 4;
  float4 a4 = *(const float4*)(A + base);
  float4 p4 = *(const float4*)(pos + pbase);
  float4 b4 = *(const float4*)(Bp + base);
  float x0 = a4.x + p4.x, x1 = a4.y + p4.y, x2 = a4.z + p4.z, x3 = a4.w + p4.w;
  float v0 = x0 + b4.x, v1 = x1 + b4.y, v2 = x2 + b4.z, v3 = x3 + b4.w;
  float sum = v0 + v1 + v2 + v3;
#pragma unroll
  for (int off = 1; off < 64; off <<= 1) sum += __shfl_xor(sum, off);
  float mean = sum * (1.f / D);
  float d0 = v0 - mean, d1 = v1 - mean, d2 = v2 - mean, d3 = v3 - mean;
  float vsum = d0 * d0 + d1 * d1 + d2 * d2 + d3 * d3;
#pragma unroll
  for (int off = 1; off < 64; off <<= 1) vsum += __shfl_xor(vsum, off);
  float inv_std = 1.0f / sqrtf(vsum * (1.f / D) + 1e-5f);
  float4 g4 = *(const float4*)(g + lane * 4);
  float4 bb4 = *(const float4*)(b + lane * 4);
  float4 o4;
  o4.x = d0 * inv_std * g4.x + bb4.x;
  o4.y = d1 * inv_std * g4.y + bb4.y;
  o4.z = d2 * inv_std * g4.z + bb4.z;
  o4.w = d3 * inv_std * g4.w + bb4.w;
  *(float4*)(out + base) = o4;
}

// ---------------- deformable attention v4: 4 queries per block (fused, verified) ----------------
__global__ __launch_bounds__(256) void deform_kernel(
    const float* __restrict__ bev, const float* __restrict__ offB,
    const float* __restrict__ awB, const float* __restrict__ dvW,
    const float* __restrict__ dvb, float* __restrict__ dtmp) {
  const int bq0 = blockIdx.x * 4;
  const int n = bq0 / Q;
  const int t = threadIdx.x;

  __shared__ float aw_s[4][NH * P];
  __shared__ int   idx_s[4][NH * P * 4];
  __shared__ float w_s[4][NH * P * 4];
  __shared__ float agg_s[4][NH][D];
  __shared__ float red_s[4][4][D];

  if (t < 128) {
    int qq = t >> 5, e = t & 31;
    int bq = bq0 + qq;
    int qi = bq - n * Q;
    // reference point: XLA f32 linspace, reciprocal-multiply delta (verified)
    float tq = __fmul_rn((float)qi, 44.492767333984375f);
    int ir = (int)rintf(tq);
    float rx = (float)(ir % WB);
    float ry = (float)(ir / WB);
    float ox = offB[(size_t)bq * 64 + e * 2 + 0];
    float oy = offB[(size_t)bq * 64 + e * 2 + 1];
    float lx = fminf(fmaxf(rx + ox, 0.f), (float)(WB - 1));
    float ly = fminf(fmaxf(ry + oy, 0.f), (float)(HB - 1));
    float x0 = floorf(lx), y0 = floorf(ly);
    float x1 = fminf(x0 + 1.f, (float)(WB - 1));
    float y1 = fminf(y0 + 1.f, (float)(HB - 1));
    float wx = lx - x0, wy = ly - y0;
    int b4 = e * 4;
    idx_s[qq][b4 + 0] = (int)y0 * WB + (int)x0; w_s[qq][b4 + 0] = (1.f - wx) * (1.f - wy);
    idx_s[qq][b4 + 1] = (int)y0 * WB + (int)x1; w_s[qq][b4 + 1] = wx * (1.f - wy);
    idx_s[qq][b4 + 2] = (int)y1 * WB + (int)x0; w_s[qq][b4 + 2] = (1.f - wx) * wy;
    idx_s[qq][b4 + 3] = (int)y1 * WB + (int)x1; w_s[qq][b4 + 3] = wx * wy;
  } else if (t < 160) {
    int idx = t - 128;
    int qq = idx >> 3, hh = idx & 7;
    const float* ap = awB + (size_t)(bq0 + qq) * 32 + hh * P;
    float l0 = ap[0], l1 = ap[1], l2 = ap[2], l3 = ap[3];
    float mx = fmaxf(fmaxf(l0, l1), fmaxf(l2, l3));
    float e0 = expf(l0 - mx), e1 = expf(l1 - mx), e2 = expf(l2 - mx), e3 = expf(l3 - mx);
    float inv = 1.f / (e0 + e1 + e2 + e3);
    aw_s[qq][hh * P + 0] = e0 * inv; aw_s[qq][hh * P + 1] = e1 * inv;
    aw_s[qq][hh * P + 2] = e2 * inv; aw_s[qq][hh * P + 3] = e3 * inv;
  }
  __syncthreads();

  {
    const float* bevn = bev + (size_t)n * HW * D;
    const int wv = t >> 6, lane = t & 63;
    const int c4 = lane * 4;
#pragma unroll
    for (int u = 0; u < 8; ++u) {
      int pid = wv + u * 4;
      int qq = pid >> 3, h = pid & 7;
      f32x4 acc = {0.f, 0.f, 0.f, 0.f};
#pragma unroll
      for (int p = 0; p < P; ++p) {
        int e = h * P + p;
        float aw = aw_s[qq][e];
        const int* ix = &idx_s[qq][e * 4];
        const float* wsp = &w_s[qq][e * 4];
        float4 g0 = *(const float4*)(bevn + (size_t)ix[0] * D + c4);
        float4 g1 = *(const float4*)(bevn + (size_t)ix[1] * D + c4);
        float4 g2 = *(const float4*)(bevn + (size_t)ix[2] * D + c4);
        float4 g3 = *(const float4*)(bevn + (size_t)ix[3] * D + c4);
        acc[0] += aw * (wsp[0] * g0.x + wsp[1] * g1.x + wsp[2] * g2.x + wsp[3] * g3.x);
        acc[1] += aw * (wsp[0] * g0.y + wsp[1] * g1.y + wsp[2] * g2.y + wsp[3] * g3.y);
        acc[2] += aw * (wsp[0] * g0.z + wsp[1] * g1.z + wsp[2] * g2.z + wsp[3] * g3.z);
        acc[3] += aw * (wsp[0] * g0.w + wsp[1] * g1.w + wsp[2] * g2.w + wsp[3] * g3.w);
      }
      *(f32x4*)&agg_s[qq][h][c4] = acc;
    }
  }
  __syncthreads();

  {
    const int chunk = t >> 6;
    const int col4 = t & 63;
    const int tt0 = col4 * 4;
    const int h = tt0 >> 5;
    f32x4 p[4] = {{0.f,0.f,0.f,0.f},{0.f,0.f,0.f,0.f},{0.f,0.f,0.f,0.f},{0.f,0.f,0.f,0.f}};
#pragma unroll 4
    for (int dd4 = 0; dd4 < 64; dd4 += 4) {
      int dd = chunk * 64 + dd4;
      float4 w0 = *(const float4*)(dvW + (size_t)(dd + 0) * D + tt0);
      float4 w1 = *(const float4*)(dvW + (size_t)(dd + 1) * D + tt0);
      float4 w2 = *(const float4*)(dvW + (size_t)(dd + 2) * D + tt0);
      float4 w3 = *(const float4*)(dvW + (size_t)(dd + 3) * D + tt0);
#pragma unroll
      for (int qq = 0; qq < 4; ++qq) {
        float4 a = *(const float4*)&agg_s[qq][h][dd];
        p[qq][0] += a.x * w0.x + a.y * w1.x + a.z * w2.x + a.w * w3.x;
        p[qq][1] += a.x * w0.y + a.y * w1.y + a.z * w2.y + a.w * w3.y;
        p[qq][2] += a.x * w0.z + a.y * w1.z + a.z * w2.z + a.w * w3.z;
        p[qq][3] += a.x * w0.w + a.y * w1.w + a.z * w2.w + a.w * w3.w;
      }
    }
#pragma unroll
    for (int qq = 0; qq < 4; ++qq) *(f32x4*)&red_s[qq][chunk][tt0] = p[qq];
  }
  __syncthreads();
  {
    float bs = dvb[t];
#pragma unroll
    for (int qq = 0; qq < 4; ++qq) {
      dtmp[(size_t)(bq0 + qq) * D + t] =
          bs + red_s[qq][0][t] + red_s[qq][1][t] + red_s[qq][2][t] + red_s[qq][3][t];
    }
  }
}

// ---------------- small elementwise kernels ----------------
__global__ void bcast_q_kernel(const float* __restrict__ pos, float* __restrict__ out) {
  for (size_t i = (size_t)blockIdx.x * blockDim.x + threadIdx.x; i < (size_t)NQD;
       i += (size_t)gridDim.x * blockDim.x)
    out[i] = pos[i % QD];
}
__global__ void finalize_kernel(const float* __restrict__ lr5, float* __restrict__ det,
                                float* __restrict__ mask) {
  int i = blockIdx.x * blockDim.x + threadIdx.x;
  if (i < NQ * ODIM) det[i] = lr5[i];
  if (i < NQ) mask[i] = (lr5[(size_t)i * ODIM] >= 0.5f) ? 1.0f : 0.0f;
}

// ---------------- host ----------------
extern "C" void kernel_launch(void* const* d_in, const int* in_sizes, int n_in,
                              void* d_out, int out_size, void* d_ws, size_t ws_size,
                              hipStream_t stream) {
  const float* bev  = (const float*)d_in[0];
  const float* pos  = (const float*)d_in[1];
  const float* Wq   = (const float*)d_in[2];  const float* bq  = (const float*)d_in[3];
  const float* Wk   = (const float*)d_in[4];  const float* bk  = (const float*)d_in[5];
  const float* Wv   = (const float*)d_in[6];  const float* bv  = (const float*)d_in[7];
  const float* Wo   = (const float*)d_in[8];  const float* bo  = (const float*)d_in[9];
  const float* ln1g = (const float*)d_in[10]; const float* ln1b = (const float*)d_in[11];
  const float* ln2g = (const float*)d_in[12]; const float* ln2b = (const float*)d_in[13];
  const float* ln3g = (const float*)d_in[14]; const float* ln3b = (const float*)d_in[15];
  const float* dvW  = (const float*)d_in[16]; const float* dvb = (const float*)d_in[17];
  const float* offW = (const float*)d_in[18]; const float* offb = (const float*)d_in[19];
  const float* awW  = (const float*)d_in[20]; const float* awb = (const float*)d_in[21];
  const float* doW  = (const float*)d_in[22]; const float* dob = (const float*)d_in[23];
  const float* f1W  = (const float*)d_in[24]; const float* f1b = (const float*)d_in[25];
  const float* f2W  = (const float*)d_in[26]; const float* f2b = (const float*)d_in[27];
  const float* dW1  = (const float*)d_in[28]; const float* db1 = (const float*)d_in[29];
  const float* dW2  = (const float*)d_in[30]; const float* db2 = (const float*)d_in[31];

  float* w = (float*)d_ws;
  float* b0 = w + 0 * (size_t)NQD;   // o -> offB/awB -> x3
  float* b1 = w + 1 * (size_t)NQD;   // q/k bf16 -> a -> d -> ffh(lo) -> deth
  float* b2 = w + 2 * (size_t)NQD;   // v bf16 -> x2 -> ffh(hi)
  float* b3 = w + 3 * (size_t)NQD;   // dtmp -> f
  float* ffh = b1;                   // spans b1..b2
  float* offB = b0;                  // NQ*64
  float* awB  = b0 + (size_t)NQ * 64;
  unsigned short* qb16 = (unsigned short*)b1;
  unsigned short* kb16 = (unsigned short*)b1 + NQD;
  unsigned short* vb16 = (unsigned short*)b2;

  float* out_output = (float*)d_out;
  float* out_det    = out_output + (size_t)NQD;
  float* out_mask   = out_det + (size_t)NQ * ODIM;
  float* out_lr     = out_mask + (size_t)NQ;

  const dim3 blk256(256);
  const dim3 blk64(64);
  const dim3 qkvGrid((NQ + TM - 1) / TM, 12);
  const dim3 gemmGridD((NQ + TM - 1) / TM, D / TN);
  const dim3 gemmGridFF((NQ + TM - 1) / TM, FF / TN);
  const dim3 offawGrid((NQ + TMT - 1) / TMT, 6);
  const dim3 thinGridDet((NQ + TMT - 1) / TMT, 2);
  const dim3 attnGrid((Q + 15) / 16, NH, N);     // 57 x 8 x 8 one-wave blocks
  const dim3 lnGrid(NQ / 4);
  const dim3 defGrid(NQ / 4);
  const int ewGrid = 1024;

  bcast_q_kernel<<<ewGrid, blk256, 0, stream>>>(pos, out_output);

  for (int i = 0; i < L; ++i) {
    const size_t wDD = (size_t)i * D * D;
    // q,k,v (bf16 outputs; A = output + pos computed on the fly)
    gemm_qkv_kernel<<<qkvGrid, blk256, 0, stream>>>(out_output, pos,
        Wq + wDD, bq + (size_t)i * D, Wk + wDD, bk + (size_t)i * D,
        Wv + wDD, bv + (size_t)i * D, qb16, kb16, vb16);
    // attention -> o (b0)
    attn_kernel<<<attnGrid, blk64, 0, stream>>>(qb16, kb16, vb16, b0);
    // a = o @ Wo + bo -> b1 (q/k bf16 dead)
    gemm_kernel<0><<<gemmGridD, blk256, 0, stream>>>(b0, Wo + wDD, bo + (size_t)i * D, b1, NQ, D, D);
    // x2 = LN1(output + pos + a) -> b2 (v bf16 dead)
    ln_add3_kernel<<<lnGrid, blk256, 0, stream>>>(out_output, pos, b1,
        ln1g + (size_t)i * D, ln1b + (size_t)i * D, b2);
    // off + aw logits -> offB/awB (b0; o dead)
    gemm_offaw_kernel<<<offawGrid, blk256, 0, stream>>>(b2,
        offW + (size_t)i * D * 64, offb + (size_t)i * 64,
        awW + (size_t)i * D * 32, awb + (size_t)i * 32, offB, awB);
    // deform (fused, 4 queries/block) -> b3
    deform_kernel<<<defGrid, blk256, 0, stream>>>(bev, offB, awB, dvW + wDD, dvb + (size_t)i * D, b3);
    // d = dtmp @ do_W + do_b -> b1
    gemm_kernel<0><<<gemmGridD, blk256, 0, stream>>>(b3, doW + wDD, dob + (size_t)i * D, b1, NQ, D, D);
    // x3 = LN2(x2 + d) -> b0
    ln_add_kernel<<<lnGrid, blk256, 0, stream>>>(b2, b1, ln2g + (size_t)i * D, ln2b + (size_t)i * D, b0);
    // FFN
    gemm_kernel<1><<<gemmGridFF, blk256, 0, stream>>>(b0, f1W + (size_t)i * D * FF, f1b + (size_t)i * FF, ffh, NQ, D, FF);
    gemm_kernel<0><<<gemmGridD, blk256, 0, stream>>>(ffh, f2W + (size_t)i * FF * D, f2b + (size_t)i * D, b3, NQ, FF, D);
    // output = LN3(x3 + f) -> out_output
    ln_add_kernel<<<lnGrid, blk256, 0, stream>>>(b0, b3, ln3g + (size_t)i * D, ln3b + (size_t)i * D, out_output);
    // det head
    gemm_kernel<1><<<gemmGridD, blk256, 0, stream>>>(out_output, dW1, db1, b1, NQ, D, D);
    gemm_thin_kernel<2><<<thinGridDet, blk256, 0, stream>>>(b1, dW2, db2, out_lr + (size_t)i * NQ * ODIM, NQ, D, ODIM);
  }

  finalize_kernel<<<(NQ * ODIM + 255) / 256, blk256, 0, stream>>>(out_lr + (size_t)(L - 1) * NQ * ODIM,
                                                                  out_det, out_mask);
}